// Round 1
// baseline (264.787 us; speedup 1.0000x reference)
//
#include <hip/hip_runtime.h>

// XGate(s=1, index=3, dim=3, N=14), batch=8, fp32.
// out.reshape(L,DIM,R,B)[l,j,r,b] = x.reshape(L,DIM,R,B)[l,(j-1)%3,r,b]
// Each (l,j) slab is a contiguous run of R*B floats -> permuted memcpy.
// src slab offset relative to dst slab: j==0 -> +2 slabs, j==1,2 -> -1 slab.
//
// R1: temporal loads (input may be LLC-resident; NT load would bypass
//     allocation), NT stores (write-once, keep LLC clean for the input);
//     UNROLL 4->8 for deeper per-wave MLP (128 B in flight per lane).

typedef float f4 __attribute__((ext_vector_type(4)));

constexpr int DIMQ    = 3;
constexpr int LBLK    = 27;               // 3^3
constexpr int RBLK    = 59049;            // 3^10
constexpr int BATCH   = 8;
constexpr int CHUNK_F = RBLK * BATCH;     // 472392 floats per (l,j) slab
constexpr int CHUNK_V = CHUNK_F / 4;      // 118098 float4 per slab (16B-aligned)
constexpr int NCHUNK  = LBLK * DIMQ;      // 81 slabs

constexpr int BLOCK  = 256;
constexpr int UNROLL = 8;
constexpr int TILE   = BLOCK * UNROLL;                    // 2048 float4 per block
constexpr int GX     = (CHUNK_V + TILE - 1) / TILE;       // 58

__global__ __launch_bounds__(BLOCK) void xgate_roll_kernel(
        const f4* __restrict__ in, f4* __restrict__ out) {
    const int chunk = blockIdx.y;                 // destination slab index
    const int j = chunk % 3;                      // wave-uniform (scalar unit)
    const int dst_base = chunk * CHUNK_V;
    const int src_base = dst_base + (j == 0 ? 2 * CHUNK_V : -CHUNK_V);

    const int v0 = blockIdx.x * TILE + (int)threadIdx.x;

    if (v0 + (UNROLL - 1) * BLOCK < CHUNK_V) {    // full tile: 8 independent 16B streams
        f4 r[UNROLL];
#pragma unroll
        for (int k = 0; k < UNROLL; ++k)
            r[k] = in[src_base + v0 + k * BLOCK];             // temporal load
#pragma unroll
        for (int k = 0; k < UNROLL; ++k)
            __builtin_nontemporal_store(r[k], &out[dst_base + v0 + k * BLOCK]);
    } else {                                      // tail of the slab
#pragma unroll
        for (int k = 0; k < UNROLL; ++k) {
            const int v = v0 + k * BLOCK;
            if (v < CHUNK_V) {
                f4 r = in[src_base + v];
                __builtin_nontemporal_store(r, &out[dst_base + v]);
            }
        }
    }
}

extern "C" void kernel_launch(void* const* d_in, const int* in_sizes, int n_in,
                              void* d_out, int out_size, void* d_ws, size_t ws_size,
                              hipStream_t stream) {
    const f4* x = (const f4*)d_in[0];
    f4* out = (f4*)d_out;
    dim3 block(BLOCK);
    dim3 grid(GX, NCHUNK);
    xgate_roll_kernel<<<grid, block, 0, stream>>>(x, out);
}

// Round 2
// 261.768 us; speedup vs baseline: 1.0115x; 1.0115x over previous
//
#include <hip/hip_runtime.h>

// XGate(s=1, index=3, dim=3, N=14), batch=8, fp32.
// out.reshape(L,DIM,R,B)[l,j,r,b] = x.reshape(L,DIM,R,B)[l,(j-1)%3,r,b]
// Each (l,j) slab is a contiguous run of R*B floats -> permuted memcpy.
// src slab offset relative to dst slab: j==0 -> +2 slabs, j==1,2 -> -1 slab.
//
// R2: fully temporal loads AND stores (match m13's 6.3 TB/s float4-copy
//     config). Rationale: harness fill leaves the output's lines dirty in
//     L2/LLC; temporal stores update them in-cache (single writeback),
//     while R0/R1's NT stores fought those dirty lines at ~1.6 TB/s.
//     UNROLL back to 4 (R1's UNROLL=8 serialized: only 24 VGPRs allocated,
//     cannot hold 8 in-flight float4).

typedef float f4 __attribute__((ext_vector_type(4)));

constexpr int DIMQ    = 3;
constexpr int LBLK    = 27;               // 3^3
constexpr int RBLK    = 59049;            // 3^10
constexpr int BATCH   = 8;
constexpr int CHUNK_F = RBLK * BATCH;     // 472392 floats per (l,j) slab
constexpr int CHUNK_V = CHUNK_F / 4;      // 118098 float4 per slab (16B-aligned)
constexpr int NCHUNK  = LBLK * DIMQ;      // 81 slabs

constexpr int BLOCK  = 256;
constexpr int UNROLL = 4;
constexpr int TILE   = BLOCK * UNROLL;                    // 1024 float4 per block
constexpr int GX     = (CHUNK_V + TILE - 1) / TILE;       // 116

__global__ __launch_bounds__(BLOCK) void xgate_roll_kernel(
        const f4* __restrict__ in, f4* __restrict__ out) {
    const int chunk = blockIdx.y;                 // destination slab index
    const int j = chunk % 3;                      // wave-uniform (scalar unit)
    const int dst_base = chunk * CHUNK_V;
    const int src_base = dst_base + (j == 0 ? 2 * CHUNK_V : -CHUNK_V);

    const int v0 = blockIdx.x * TILE + (int)threadIdx.x;

    if (v0 + (UNROLL - 1) * BLOCK < CHUNK_V) {    // full tile: 4 independent 16B streams
        f4 r[UNROLL];
#pragma unroll
        for (int k = 0; k < UNROLL; ++k)
            r[k] = in[src_base + v0 + k * BLOCK];         // temporal load
#pragma unroll
        for (int k = 0; k < UNROLL; ++k)
            out[dst_base + v0 + k * BLOCK] = r[k];        // temporal store
    } else {                                      // tail of the slab
#pragma unroll
        for (int k = 0; k < UNROLL; ++k) {
            const int v = v0 + k * BLOCK;
            if (v < CHUNK_V) {
                out[dst_base + v] = in[src_base + v];
            }
        }
    }
}

extern "C" void kernel_launch(void* const* d_in, const int* in_sizes, int n_in,
                              void* d_out, int out_size, void* d_ws, size_t ws_size,
                              hipStream_t stream) {
    const f4* x = (const f4*)d_in[0];
    f4* out = (f4*)d_out;
    dim3 block(BLOCK);
    dim3 grid(GX, NCHUNK);
    xgate_roll_kernel<<<grid, block, 0, stream>>>(x, out);
}

// Round 3
// 260.740 us; speedup vs baseline: 1.0155x; 1.0039x over previous
//
#include <hip/hip_runtime.h>

// XGate(s=1, index=3, dim=3, N=14), batch=8, fp32.
// out.reshape(L,DIM,R,B)[l,j,r,b] = x.reshape(L,DIM,R,B)[l,(j-1)%3,r,b]
// Each (l,j) slab is a contiguous run of R*B floats -> permuted memcpy.
// src slab offset relative to dst slab: j==0 -> +2 slabs, j==1,2 -> -1 slab.
//
// R3: back to NT load + NT store (R0's hint set — best measured; temporal
//     variants R1/R2 both slower). Structural change: resident grid-stride.
//     grid = 24 x 81 = 1944 blocks (all co-resident at 4 waves/block on
//     256 CUs) instead of 9396 one-shot 16KB blocks. Each block sweeps its
//     slab with a software-pipelined loop: next tile's 4 loads issue before
//     current tile's 4 stores -> 4-8 loads continuously in flight per wave,
//     no wave teardown churn, no dispatch ramp (R0/R1 showed only 63%
//     occupancy from churn).

typedef float f4 __attribute__((ext_vector_type(4)));

constexpr int DIMQ    = 3;
constexpr int LBLK    = 27;               // 3^3
constexpr int RBLK    = 59049;            // 3^10
constexpr int BATCH   = 8;
constexpr int CHUNK_F = RBLK * BATCH;     // 472392 floats per (l,j) slab
constexpr int CHUNK_V = CHUNK_F / 4;      // 118098 float4 per slab (16B-aligned)
constexpr int NCHUNK  = LBLK * DIMQ;      // 81 slabs

constexpr int BLOCK  = 256;
constexpr int UNROLL = 4;
constexpr int TILE   = BLOCK * UNROLL;    // 1024 float4 per tile
constexpr int GX     = 24;                // blocks per slab; 24*81=1944 resident
constexpr int STRIDE = GX * TILE;         // 24576 float4 sweep stride

__global__ __launch_bounds__(BLOCK) void xgate_roll_kernel(
        const f4* __restrict__ in, f4* __restrict__ out) {
    const int chunk = blockIdx.y;                 // destination slab index
    const int j = chunk % 3;                      // wave-uniform (scalar unit)
    const int dst_base = chunk * CHUNK_V;
    const int src_base = dst_base + (j == 0 ? 2 * CHUNK_V : -CHUNK_V);

    int v = blockIdx.x * TILE + (int)threadIdx.x;

    if (v + (UNROLL - 1) * BLOCK < CHUNK_V) {
        // software-pipelined steady state over full tiles
        f4 r[UNROLL];
#pragma unroll
        for (int k = 0; k < UNROLL; ++k)
            r[k] = __builtin_nontemporal_load(&in[src_base + v + k * BLOCK]);

        int vn = v + STRIDE;
        while (vn + (UNROLL - 1) * BLOCK < CHUNK_V) {
            f4 s[UNROLL];
#pragma unroll
            for (int k = 0; k < UNROLL; ++k)      // prefetch next tile first
                s[k] = __builtin_nontemporal_load(&in[src_base + vn + k * BLOCK]);
#pragma unroll
            for (int k = 0; k < UNROLL; ++k)      // then drain current tile
                __builtin_nontemporal_store(r[k], &out[dst_base + v + k * BLOCK]);
#pragma unroll
            for (int k = 0; k < UNROLL; ++k)
                r[k] = s[k];
            v = vn;
            vn += STRIDE;
        }
#pragma unroll
        for (int k = 0; k < UNROLL; ++k)
            __builtin_nontemporal_store(r[k], &out[dst_base + v + k * BLOCK]);
        v = vn;
    }

    // tail: at most one partial tile per thread (tile span 768 < STRIDE)
#pragma unroll
    for (int k = 0; k < UNROLL; ++k) {
        const int vv = v + k * BLOCK;
        if (vv < CHUNK_V) {
            f4 r = __builtin_nontemporal_load(&in[src_base + vv]);
            __builtin_nontemporal_store(r, &out[dst_base + vv]);
        }
    }
}

extern "C" void kernel_launch(void* const* d_in, const int* in_sizes, int n_in,
                              void* d_out, int out_size, void* d_ws, size_t ws_size,
                              hipStream_t stream) {
    const f4* x = (const f4*)d_in[0];
    f4* out = (f4*)d_out;
    dim3 block(BLOCK);
    dim3 grid(GX, NCHUNK);
    xgate_roll_kernel<<<grid, block, 0, stream>>>(x, out);
}

// Round 4
// 247.555 us; speedup vs baseline: 1.0696x; 1.0533x over previous
//
#include <hip/hip_runtime.h>

// XGate(s=1, index=3, dim=3, N=14), batch=8, fp32.
// out.reshape(L,DIM,R,B)[l,j,r,b] = x.reshape(L,DIM,R,B)[l,(j-1)%3,r,b]
// Each (l,j) slab is a contiguous run of R*B floats -> permuted memcpy.
// src slab offset relative to dst slab: j==0 -> +2 slabs, j==1,2 -> -1 slab.
//
// R4: one-shot blocks (best structure: R0 ~78us vs resident-loop R3 ~91us),
//     NT load + NT store (best hint set: temporal variants R1/R2 both
//     slower). New: true 8-deep per-wave load batch. R1 showed the lever:
//     compiler split UNROLL=8 into 2-deep dependent pairs (VGPR=24) -> 95us,
//     while 4-deep R0 ran 78us. Force 8 live float4 with
//     __launch_bounds__(256,8) (64-VGPR budget, still 8 waves/SIMD) plus
//     sched_barrier(0) between the load group and the store group.

typedef float f4 __attribute__((ext_vector_type(4)));

constexpr int DIMQ    = 3;
constexpr int LBLK    = 27;               // 3^3
constexpr int RBLK    = 59049;            // 3^10
constexpr int BATCH   = 8;
constexpr int CHUNK_F = RBLK * BATCH;     // 472392 floats per (l,j) slab
constexpr int CHUNK_V = CHUNK_F / 4;      // 118098 float4 per slab (16B-aligned)
constexpr int NCHUNK  = LBLK * DIMQ;      // 81 slabs

constexpr int BLOCK  = 256;
constexpr int UNROLL = 8;
constexpr int TILE   = BLOCK * UNROLL;                    // 2048 float4 per block
constexpr int GX     = (CHUNK_V + TILE - 1) / TILE;       // 58

__global__ __launch_bounds__(BLOCK, 8) void xgate_roll_kernel(
        const f4* __restrict__ in, f4* __restrict__ out) {
    const int chunk = blockIdx.y;                 // destination slab index
    const int j = chunk % 3;                      // wave-uniform (scalar unit)
    const int dst_base = chunk * CHUNK_V;
    const int src_base = dst_base + (j == 0 ? 2 * CHUNK_V : -CHUNK_V);

    const int v0 = blockIdx.x * TILE + (int)threadIdx.x;

    if (v0 + (UNROLL - 1) * BLOCK < CHUNK_V) {    // full tile: 8 independent 16B streams
        f4 r[UNROLL];
#pragma unroll
        for (int k = 0; k < UNROLL; ++k)
            r[k] = __builtin_nontemporal_load(&in[src_base + v0 + k * BLOCK]);
        __builtin_amdgcn_sched_barrier(0);        // no store may hoist into the load batch
#pragma unroll
        for (int k = 0; k < UNROLL; ++k)
            __builtin_nontemporal_store(r[k], &out[dst_base + v0 + k * BLOCK]);
    } else {                                      // tail of the slab
#pragma unroll
        for (int k = 0; k < UNROLL; ++k) {
            const int v = v0 + k * BLOCK;
            if (v < CHUNK_V) {
                f4 r = __builtin_nontemporal_load(&in[src_base + v]);
                __builtin_nontemporal_store(r, &out[dst_base + v]);
            }
        }
    }
}

extern "C" void kernel_launch(void* const* d_in, const int* in_sizes, int n_in,
                              void* d_out, int out_size, void* d_ws, size_t ws_size,
                              hipStream_t stream) {
    const f4* x = (const f4*)d_in[0];
    f4* out = (f4*)d_out;
    dim3 block(BLOCK);
    dim3 grid(GX, NCHUNK);
    xgate_roll_kernel<<<grid, block, 0, stream>>>(x, out);
}